// Round 7
// baseline (139.177 us; speedup 1.0000x reference)
//
#include <hip/hip_runtime.h>

#define BATCH 4
#define NPTS  2048
#define DZDIM 128
#define GD    128
#define M_TOT (GD*GD)
#define TN    32
#define ZP    2112      // zt/FX/FY/xs row pitch (elements): 2048 + 64 zeroed tail, 64B-aligned
#define WBIN  15        // +-15 bins: w < 7e-6 outside

typedef __attribute__((ext_vector_type(8))) __bf16 bf16x8;
typedef __attribute__((ext_vector_type(4))) float floatx4;
typedef __attribute__((ext_vector_type(4))) unsigned int uintx4;

__device__ __forceinline__ unsigned int f2bf_bits(float x){
  unsigned int u = __float_as_uint(x);
  u += 0x7FFFu + ((u >> 16) & 1u);
  return u >> 16;
}
__device__ __forceinline__ int point_bin(float px){
  int bin = __float2int_rn((px + 2.0f) * (127.0f / 4.0f));
  return min(GD - 1, max(0, bin));
}

// bf16x8 product of two bf16x8 (as uintx4): unpack-via-bitops, f32 mul, truncation pack.
__device__ __forceinline__ bf16x8 bfmul8(uintx4 a, uintx4 b){
  uintx4 r;
#pragma unroll
  for (int j = 0; j < 4; ++j){
    float alo = __uint_as_float(a[j] << 16);
    float ahi = __uint_as_float(a[j] & 0xffff0000u);
    float blo = __uint_as_float(b[j] << 16);
    float bhi = __uint_as_float(b[j] & 0xffff0000u);
    unsigned int plo = __float_as_uint(alo * blo);
    unsigned int phi = __float_as_uint(ahi * bhi);
    r[j] = (plo >> 16) | (phi & 0xffff0000u);
  }
  union { uintx4 u; bf16x8 v; } cv; cv.u = r;
  return cv.v;
}

// ---- prep: hist+scan (0..3) | x_grid bcast (4..131) | xs tail (132) | zt tail (133,134) ----
__global__ __launch_bounds__(256) void prep_kernel(
    const float* __restrict__ x, const float* __restrict__ grid,
    float* __restrict__ out, int* __restrict__ binStart,
    float2* __restrict__ xs, unsigned short* __restrict__ zt)
{
  const int tid = threadIdx.x;
  const int bx  = blockIdx.x;
  if (bx < BATCH){
    __shared__ int h[GD];
    __shared__ int s[GD + 1];
    const int b = bx;
    if (tid < GD) h[tid] = 0;
    __syncthreads();
    for (int n = tid; n < NPTS; n += 256)
      atomicAdd(&h[point_bin(x[(b*NPTS + n)*2])], 1);
    __syncthreads();
    if (tid == 0){
      int acc = 0;
#pragma unroll
      for (int j = 0; j < GD; ++j){ s[j] = acc; acc += h[j]; }
      s[GD] = acc;
    }
    __syncthreads();
    if (tid <= GD) binStart[b*(GD+1) + tid] = s[tid];
  } else if (bx < BATCH + 128){
    int idx = (bx - BATCH) * 256 + tid;       // 0..32767 == GD*GD*2
    float g = grid[idx];
#pragma unroll
    for (int b = 0; b < BATCH; ++b) out[b*(GD*GD*2) + idx] = g;
  } else if (bx == BATCH + 128){
    int b = tid >> 6, j = tid & 63;
    xs[(size_t)b*ZP + NPTS + j] = make_float2(0.f, 0.f);
  } else {
    // zt tail: 512 rows x 128 B -> 0 ; 2 blocks x 256 rows
    int row = (bx - (BATCH + 129)) * 256 + tid;   // 0..511 == b*128+dz
    uintx4 zv = {0u, 0u, 0u, 0u};
    uintx4* p = (uintx4*)&zt[(size_t)row*ZP + NPTS];
#pragma unroll
    for (int c = 0; c < 8; ++c) p[c] = zv;
  }
}

// ---- stable scatter into bin-sorted arrays: xs (float2) + perm ----
__global__ __launch_bounds__(256) void scatter_kernel(const float* __restrict__ x,
                                                      const int* __restrict__ binStart,
                                                      float2* __restrict__ xs,
                                                      int* __restrict__ perm){
  const int b = blockIdx.y;
  const int wv = threadIdx.x >> 6, lane = threadIdx.x & 63;
  const int bin = blockIdx.x * 4 + wv;
  int base = binStart[b*(GD+1) + bin];
  const float2* __restrict__ x2 = (const float2*)x;
  for (int n0 = 0; n0 < NPTS; n0 += 64){
    int n = n0 + lane;
    float2 xv = x2[b*NPTS + n];
    bool keep = (point_bin(xv.x) == bin);
    unsigned long long mask = __ballot(keep);
    int pre = __popcll(mask & ((1ull << lane) - 1ull));
    if (keep){
      xs[(long)b*ZP + base + pre] = xv;
      perm[b*NPTS + base + pre]   = n;
    }
    base += __popcll(mask);
  }
}

// ---- combined: bid<256 -> zt build ; bid>=256 -> FX/FY weight-factor tables ----
// zt[b][dz][j] = bf16(z[b][perm[j]][dz])
// FX[b][i][k]  = bf16(exp2(c0*(gx_i - xs.x)^2)), FY[b][mr][k] = bf16(exp2(c1*(gy_mr - xs.y)^2))
__global__ __launch_bounds__(256) void build_kernel(
    const float* __restrict__ z, const int* __restrict__ perm,
    const float2* __restrict__ xs, const float* __restrict__ lsp,
    unsigned short* __restrict__ zt,
    unsigned short* __restrict__ FX, unsigned short* __restrict__ FY)
{
  const int tid = threadIdx.x;
  const int bid = blockIdx.x;
  if (bid < 256){
    const int by = bid >> 5;             // b*2 + half
    const int b = by >> 1, half = by & 1;
    const int j0 = (bid & 31) * 64;
    const int jj = tid & 63;
    const int dq = tid >> 6;             // 0..3
    const int j  = j0 + jj;
    const int n  = perm[b*NPTS + j];
    const float4* __restrict__ z4 = (const float4*)z;
    const long rb = (long)(b*NPTS + n) * 32;
#pragma unroll
    for (int r = 0; r < 4; ++r){
      int c = half*16 + dq*4 + r;        // float4 chunk -> dz = 4c..4c+3
      float4 v = z4[rb + c];
      long o = ((long)(b*DZDIM + 4*c) * ZP) + j;
      zt[o        ] = (unsigned short)f2bf_bits(v.x);
      zt[o +   ZP ] = (unsigned short)f2bf_bits(v.y);
      zt[o + 2*ZP ] = (unsigned short)f2bf_bits(v.z);
      zt[o + 3*ZP ] = (unsigned short)f2bf_bits(v.w);
    }
  } else {
    const int tb   = bid - 256;          // 0..1023
    const int tbl  = tb & 1;             // 0=FX (x-coord), 1=FY (y-coord)
    const int b    = (tb >> 1) & 3;
    const int row  = tb >> 3;            // 0..127
    const float step = 4.0f / 127.0f;
    const float g = -2.0f + (float)row * step;
    const float l0 = 1e-5f + log1pf(expf(lsp[0]));
    const float l1 = 1e-5f + log1pf(expf(lsp[1]));
    const float LOG2E = 1.4426950408889634f;
    const float c = tbl ? (-0.5f * LOG2E / (l1*l1)) : (-0.5f * LOG2E / (l0*l0));
    unsigned short* __restrict__ T = (tbl ? FY : FX) + (size_t)(b*GD + row)*ZP;
    const int k0 = tid * 8;
    const float4* __restrict__ p4 = (const float4*)(xs + (size_t)b*ZP + k0);
    unsigned int u[4];
#pragma unroll
    for (int j = 0; j < 4; ++j){
      float4 pp = p4[j];                 // two points: (x0,y0,x1,y1)
      float p0 = tbl ? pp.y : pp.x;
      float p1 = tbl ? pp.w : pp.z;
      float d0 = g - p0, d1 = g - p1;
      float w0 = __builtin_amdgcn_exp2f((c*d0)*d0);
      float w1 = __builtin_amdgcn_exp2f((c*d1)*d1);
      u[j] = f2bf_bits(w0) | (f2bf_bits(w1) << 16);
    }
    *(uintx4*)&T[k0] = (uintx4){u[0], u[1], u[2], u[3]};
    if (tid < 8){                        // zero tail k in [2048, 2112)
      uintx4 zv = {0u,0u,0u,0u};
      *(uintx4*)&T[NPTS + tid*8] = zv;
    }
  }
}

// ---- main: NO LDS, NO barriers, NO exp2. A = FX*FY table product; B from L1/L2.
// block = 64m x 128dz (1024 blocks); wave = 32m x 64dz; double-buffered loads.
__global__ __launch_bounds__(256, 3) void setconv_mfma_kernel(
    const unsigned short* __restrict__ FX, const unsigned short* __restrict__ FY,
    const int* __restrict__ binStart, const unsigned short* __restrict__ zt,
    float* __restrict__ outz)
{
  const int tid = threadIdx.x, lane = tid & 63, wv = tid >> 6;
  const int bid = blockIdx.x;            // 1024 blocks
  const int g   = bid & 7;               // XCD band: g owns rows [16g,16g+16)
  const int s   = bid >> 3;              // 0..127
  const int half= s & 1;                 // m half of the row
  const int b   = (s >> 1) & 3;
  const int il  = s >> 3;                // 0..15
  const int i   = g*16 + il;

  const int lo   = binStart[b*(GD+1) + max(0, i - WBIN)];
  const int hi   = binStart[b*(GD+1) + min(GD-1, i + WBIN) + 1];
  const int lo32 = lo & ~31;             // 64B-aligned k-base
  const int T    = (hi - lo32 + TN - 1) / TN;

  const int q  = lane >> 4, ml = lane & 15;
  const int mg = wv >> 1;                // wave m-group (0/1)
  const int dh = wv & 1;                 // wave dz-half
  const int m0 = half*64 + mg*32;        // wave's first m

  const unsigned short* __restrict__ fxp  = FX + (size_t)(b*GD + i)*ZP + q*8;
  const unsigned short* __restrict__ fyp0 = FY + (size_t)(b*GD + m0 + ml)*ZP + q*8;
  const unsigned short* __restrict__ fyp1 = fyp0 + (size_t)16*ZP;
  const unsigned short* __restrict__ ztp  = zt + (size_t)(b*DZDIM + dh*64 + ml)*ZP + q*8;

  floatx4 acc0[4], acc1[4];
#pragma unroll
  for (int tz = 0; tz < 4; ++tz){
    acc0[tz] = (floatx4){0.f,0.f,0.f,0.f};
    acc1[tz] = (floatx4){0.f,0.f,0.f,0.f};
  }

  uintx4 FXr[2], FY0r[2], FY1r[2];
  bf16x8 Bf[2][4];

  auto loadT = [&](int sb, int t){
    const int k = lo32 + t*TN;
    FXr[sb]  = *(const uintx4*)(fxp  + k);
    FY0r[sb] = *(const uintx4*)(fyp0 + k);
    FY1r[sb] = *(const uintx4*)(fyp1 + k);
#pragma unroll
    for (int tz = 0; tz < 4; ++tz)
      Bf[sb][tz] = *(const bf16x8*)(ztp + (size_t)(tz*16)*ZP + k);
  };
  auto stepT = [&](int sb){
    bf16x8 afa = bfmul8(FXr[sb], FY0r[sb]);
    bf16x8 afb = bfmul8(FXr[sb], FY1r[sb]);
#pragma unroll
    for (int tz = 0; tz < 4; ++tz){
      acc0[tz] = __builtin_amdgcn_mfma_f32_16x16x32_bf16(afa, Bf[sb][tz], acc0[tz], 0, 0, 0);
      acc1[tz] = __builtin_amdgcn_mfma_f32_16x16x32_bf16(afb, Bf[sb][tz], acc1[tz], 0, 0, 0);
    }
  };

  if (T > 0){
    loadT(0, 0);
    int t = 0;
    while (true){
      if (t + 1 < T) loadT(1, t + 1);
      stepT(0);
      ++t; if (t >= T) break;
      if (t + 1 < T) loadT(0, t + 1);
      stepT(1);
      ++t; if (t >= T) break;
    }
  }

  // epilogue: C/D col(dz)=ml, row(m)=q*4+r ; acc1 rows +16
  const size_t ob = ((size_t)(b*M_TOT + i*GD + m0 + q*4) << 7) + dh*64 + ml;
#pragma unroll
  for (int tz = 0; tz < 4; ++tz)
#pragma unroll
    for (int r = 0; r < 4; ++r){
      outz[ob + ((size_t)r << 7) + tz*16]        = acc0[tz][r];
      outz[ob + ((size_t)(r + 16) << 7) + tz*16] = acc1[tz][r];
    }
}

extern "C" void kernel_launch(void* const* d_in, const int* in_sizes, int n_in,
                              void* d_out, int out_size, void* d_ws, size_t ws_size,
                              hipStream_t stream)
{
  const float* x    = (const float*)d_in[0];
  const float* z    = (const float*)d_in[1];
  const float* grid = (const float*)d_in[2];
  const float* lsp  = (const float*)d_in[3];
  float* out = (float*)d_out;

  char* ws = (char*)d_ws;
  size_t off = 0;
  int*            binStart = (int*)(ws + off);            off += 4*(GD+1)*4;        // 2064
  int*            perm     = (int*)(ws + off);            off += BATCH*NPTS*4;      // 32 KB
  float2*         xs       = (float2*)(ws + off);         off += BATCH*ZP*8;        // 66 KB
  off = (off + 255) & ~(size_t)255;
  unsigned short* zt       = (unsigned short*)(ws + off); off += (size_t)BATCH*DZDIM*ZP*2; // 2.16MB
  unsigned short* FX       = (unsigned short*)(ws + off); off += (size_t)BATCH*GD*ZP*2;    // 2.16MB
  unsigned short* FY       = (unsigned short*)(ws + off);

  hipLaunchKernelGGL(prep_kernel, dim3(BATCH + 128 + 3), dim3(256), 0, stream,
                     x, grid, out, binStart, xs, zt);
  hipLaunchKernelGGL(scatter_kernel, dim3(GD/4, BATCH), dim3(256), 0, stream,
                     x, binStart, xs, perm);
  hipLaunchKernelGGL(build_kernel, dim3(256 + 1024), dim3(256), 0, stream,
                     z, perm, xs, lsp, zt, FX, FY);
  hipLaunchKernelGGL(setconv_mfma_kernel, dim3(GD*2*BATCH), dim3(256), 0, stream,
                     FX, FY, binStart, zt, out + BATCH*GD*GD*2);
}

// Round 8
// 133.678 us; speedup vs baseline: 1.0411x; 1.0411x over previous
//
#include <hip/hip_runtime.h>
#include <hip/hip_bf16.h>

#define BATCH 4
#define NPTS  2048
#define DZDIM 128
#define GD    128
#define M_TOT (GD*GD)
#define ZP    2176      // table row pitch (elements): 2048 data + 128 zero tail
#define WBIN  15        // +-15 bins: w < 7e-6 outside
#define CHK   128       // K-chunk per barrier
#define LROW  136       // LDS ushorts per dz-row: 128 data + 8 pad (272 B = 17 x 16B)
#define NSLOT (DZDIM*17)  // 16B slots per chunk buffer = 2176

typedef __attribute__((ext_vector_type(8))) __bf16 bf16x8;
typedef __attribute__((ext_vector_type(4))) float floatx4;
typedef __attribute__((ext_vector_type(4))) unsigned int uintx4;

__device__ __forceinline__ unsigned int f2bf_bits(float x){
  unsigned int u = __float_as_uint(x);
  u += 0x7FFFu + ((u >> 16) & 1u);
  return u >> 16;
}
__device__ __forceinline__ int point_bin(float px){
  int bin = __float2int_rn((px + 2.0f) * (127.0f / 4.0f));
  return min(GD - 1, max(0, bin));
}
__device__ __forceinline__ unsigned int pk_bf16(float a, float b){
  union { __hip_bfloat162 h2; unsigned int u; } cv;
  cv.h2 = __float22bfloat162_rn(make_float2(a, b));   // v_cvt_pk_bf16_f32 (RNE)
  return cv.u;
}

// ---- prep: hist+scan (0..3) | x_grid bcast (4..131) | xs tail (132) | zt tail (133,134) ----
__global__ __launch_bounds__(256) void prep_kernel(
    const float* __restrict__ x, const float* __restrict__ grid,
    float* __restrict__ out, int* __restrict__ binStart,
    float2* __restrict__ xs, unsigned short* __restrict__ zt)
{
  const int tid = threadIdx.x;
  const int bx  = blockIdx.x;
  if (bx < BATCH){
    __shared__ int h[GD];
    __shared__ int s[GD + 1];
    const int b = bx;
    if (tid < GD) h[tid] = 0;
    __syncthreads();
    for (int n = tid; n < NPTS; n += 256)
      atomicAdd(&h[point_bin(x[(b*NPTS + n)*2])], 1);
    __syncthreads();
    if (tid == 0){
      int acc = 0;
#pragma unroll
      for (int j = 0; j < GD; ++j){ s[j] = acc; acc += h[j]; }
      s[GD] = acc;
    }
    __syncthreads();
    if (tid <= GD) binStart[b*(GD+1) + tid] = s[tid];
  } else if (bx < BATCH + 128){
    int idx = (bx - BATCH) * 256 + tid;       // 0..32767 == GD*GD*2
    float g = grid[idx];
#pragma unroll
    for (int b = 0; b < BATCH; ++b) out[b*(GD*GD*2) + idx] = g;
  } else if (bx == BATCH + 128){
    // xs tail: 4 batches x 128 float2 -> (0,0)
    for (int sIdx = tid; sIdx < BATCH*128; sIdx += 256){
      int b = sIdx >> 7, j = sIdx & 127;
      xs[(size_t)b*ZP + NPTS + j] = make_float2(0.f, 0.f);
    }
  } else {
    // zt tail: 512 rows x 128 elem -> 0 ; 2 blocks x 256 rows
    int row = (bx - (BATCH + 129)) * 256 + tid;   // 0..511 == b*128+dz
    uintx4 zv = {0u, 0u, 0u, 0u};
    uintx4* p = (uintx4*)&zt[(size_t)row*ZP + NPTS];
#pragma unroll
    for (int c = 0; c < 16; ++c) p[c] = zv;
  }
}

// ---- stable scatter into bin-sorted arrays: xs (float2) + perm ----
__global__ __launch_bounds__(256) void scatter_kernel(const float* __restrict__ x,
                                                      const int* __restrict__ binStart,
                                                      float2* __restrict__ xs,
                                                      int* __restrict__ perm){
  const int b = blockIdx.y;
  const int wv = threadIdx.x >> 6, lane = threadIdx.x & 63;
  const int bin = blockIdx.x * 4 + wv;
  int base = binStart[b*(GD+1) + bin];
  const float2* __restrict__ x2 = (const float2*)x;
  for (int n0 = 0; n0 < NPTS; n0 += 64){
    int n = n0 + lane;
    float2 xv = x2[b*NPTS + n];
    bool keep = (point_bin(xv.x) == bin);
    unsigned long long mask = __ballot(keep);
    int pre = __popcll(mask & ((1ull << lane) - 1ull));
    if (keep){
      xs[(size_t)b*ZP + base + pre] = xv;
      perm[b*NPTS + base + pre]   = n;
    }
    base += __popcll(mask);
  }
}

// ---- build: bid<256 -> zt (bf16, sorted, transposed); else f32 FX/FY factor tables ----
__global__ __launch_bounds__(256) void build_kernel(
    const float* __restrict__ z, const int* __restrict__ perm,
    const float2* __restrict__ xs, const float* __restrict__ lsp,
    unsigned short* __restrict__ zt,
    float* __restrict__ FXf, float* __restrict__ FYf)
{
  const int tid = threadIdx.x;
  const int bid = blockIdx.x;
  if (bid < 256){
    const int by = bid >> 5;             // b*2 + half
    const int b = by >> 1, half = by & 1;
    const int j0 = (bid & 31) * 64;
    const int jj = tid & 63;
    const int dq = tid >> 6;             // 0..3
    const int j  = j0 + jj;
    const int n  = perm[b*NPTS + j];
    const float4* __restrict__ z4 = (const float4*)z;
    const long rb = (long)(b*NPTS + n) * 32;
#pragma unroll
    for (int r = 0; r < 4; ++r){
      int c = half*16 + dq*4 + r;        // float4 chunk -> dz = 4c..4c+3
      float4 v = z4[rb + c];
      size_t o = ((size_t)(b*DZDIM + 4*c) * ZP) + j;
      zt[o        ] = (unsigned short)f2bf_bits(v.x);
      zt[o +   ZP ] = (unsigned short)f2bf_bits(v.y);
      zt[o + 2*ZP ] = (unsigned short)f2bf_bits(v.z);
      zt[o + 3*ZP ] = (unsigned short)f2bf_bits(v.w);
    }
  } else {
    const int tb   = bid - 256;          // 0..1023
    const int tbl  = tb & 1;             // 0=FX (x-coord), 1=FY (y-coord)
    const int b    = (tb >> 1) & 3;
    const int row  = tb >> 3;            // 0..127
    const float step = 4.0f / 127.0f;
    const float g = -2.0f + (float)row * step;
    const float l0 = 1e-5f + log1pf(expf(lsp[0]));
    const float l1 = 1e-5f + log1pf(expf(lsp[1]));
    const float LOG2E = 1.4426950408889634f;
    const float c = tbl ? (-0.5f * LOG2E / (l1*l1)) : (-0.5f * LOG2E / (l0*l0));
    float* __restrict__ T = (tbl ? FYf : FXf) + (size_t)(b*GD + row)*ZP;
    const float4* __restrict__ p4 = (const float4*)(xs + (size_t)b*ZP);
    for (int sIdx = tid; sIdx < ZP/8; sIdx += 256){
      int k0 = sIdx * 8;
      float w[8];
#pragma unroll
      for (int j = 0; j < 4; ++j){
        float4 pp = p4[k0/2 + j];        // two points: (x0,y0,x1,y1)
        float p0 = tbl ? pp.y : pp.x;
        float p1 = tbl ? pp.w : pp.z;
        float d0 = g - p0, d1 = g - p1;
        w[2*j]   = __builtin_amdgcn_exp2f((c*d0)*d0);
        w[2*j+1] = __builtin_amdgcn_exp2f((c*d1)*d1);
      }
      *(float4*)(T + k0)     = make_float4(w[0], w[1], w[2], w[3]);
      *(float4*)(T + k0 + 4) = make_float4(w[4], w[5], w[6], w[7]);
    }
  }
}

// ---- main: chunked LDS pipeline. block = (b,i) = 128j x 128dz; 4 waves of 64j x 64dz.
// glds stages 128k x 128dz chunk; compute phase (~1200 cyc) >> glds latency -> barrier
// drain finds loads complete. A = FX*FY f32-table product, packed via v_cvt_pk_bf16_f32.
__global__ __launch_bounds__(256, 2) void setconv_mfma_kernel(
    const float* __restrict__ FXf, const float* __restrict__ FYf,
    const int* __restrict__ binStart, const unsigned short* __restrict__ zt,
    float* __restrict__ outz)
{
  __shared__ __align__(16) unsigned short Zl[2][DZDIM * LROW];   // 2 x 34816 B

  const int tid = threadIdx.x, lane = tid & 63, wv = tid >> 6;
  const int q  = lane >> 4, ml = lane & 15;
  const int jt = wv & 1, dt = wv >> 1;     // wave tile: j-half, d-half
  const int bid = blockIdx.x;              // 512 blocks
  const int g   = bid & 7;                 // XCD band
  const int s   = bid >> 3;
  const int b   = s & 3;
  const int il  = s >> 2;                  // 0..15
  const int i   = g*16 + il;

  const int lo   = binStart[b*(GD+1) + max(0, i - WBIN)];
  const int hi   = binStart[b*(GD+1) + min(GD-1, i + WBIN) + 1];
  const int lo32 = lo & ~31;
  const int C    = (hi - lo32 + CHK - 1) / CHK;   // chunks; k stays < ZP by construction

  const float* __restrict__ fxrow = FXf + (size_t)(b*GD + i)*ZP;
  const float* __restrict__ fyrow = FYf + (size_t)(b*GD + jt*64)*ZP;
  const unsigned short* __restrict__ ztb = zt + (size_t)b*DZDIM*ZP;

  floatx4 acc[4][4];
#pragma unroll
  for (int jf = 0; jf < 4; ++jf)
#pragma unroll
    for (int df = 0; df < 4; ++df) acc[jf][df] = (floatx4){0.f,0.f,0.f,0.f};

  auto stage = [&](int buf, int c){
    const int k0 = lo32 + c*CHK;
#pragma unroll
    for (int it = 0; it < 9; ++it){
      int sl = it*256 + tid;               // LDS dest = uniform + lane*16 (glds constraint)
      if (sl < NSLOT){
        int row = sl / 17;
        int c16 = sl - row*17; if (c16 > 15) c16 = 15;   // pad slot: dup (harmless)
        const unsigned short* gp = ztb + (size_t)row*ZP + k0 + c16*8;
        __builtin_amdgcn_global_load_lds(
            (const __attribute__((address_space(1))) unsigned int*)gp,
            (__attribute__((address_space(3))) unsigned int*)((char*)&Zl[buf][0] + (size_t)sl*16),
            16, 0, 0);
      }
    }
  };

  auto compute = [&](int buf, int c){
    const int k0 = lo32 + c*CHK;
#pragma unroll
    for (int kt = 0; kt < 4; ++kt){
      const int kabs = k0 + kt*32 + q*8;   // lane's 8 k-points
      float4 fxa = *(const float4*)(fxrow + kabs);
      float4 fxb = *(const float4*)(fxrow + kabs + 4);
      bf16x8 af[4];
#pragma unroll
      for (int jf = 0; jf < 4; ++jf){
        const float* fp = fyrow + (size_t)(jf*16 + ml)*ZP + kabs;
        float4 fya = *(const float4*)fp;
        float4 fyb = *(const float4*)(fp + 4);
        uintx4 u;
        u[0] = pk_bf16(fxa.x*fya.x, fxa.y*fya.y);
        u[1] = pk_bf16(fxa.z*fya.z, fxa.w*fya.w);
        u[2] = pk_bf16(fxb.x*fyb.x, fxb.y*fyb.y);
        u[3] = pk_bf16(fxb.z*fyb.z, fxb.w*fyb.w);
        union { uintx4 uu; bf16x8 v; } cv; cv.uu = u;
        af[jf] = cv.v;
      }
      bf16x8 bf[4];
#pragma unroll
      for (int df = 0; df < 4; ++df){
        int d = dt*64 + df*16 + ml;
        bf[df] = *(const bf16x8*)((const char*)&Zl[buf][0] + (size_t)d*272 + kt*64 + q*16);
      }
#pragma unroll
      for (int jf = 0; jf < 4; ++jf)
#pragma unroll
        for (int df = 0; df < 4; ++df)
          acc[jf][df] = __builtin_amdgcn_mfma_f32_16x16x32_bf16(af[jf], bf[df], acc[jf][df], 0, 0, 0);
    }
  };

  if (C > 0){
    stage(0, 0);
    __syncthreads();
    for (int c = 0; c < C; ++c){
      if (c + 1 < C) stage((c + 1) & 1, c + 1);   // in flight during entire compute phase
      compute(c & 1, c);
      __syncthreads();                            // drain: loads issued ~1200 cyc ago -> done
    }
  }

  // epilogue: C/D col(d)=ml, row(j)=q*4+r
  const size_t ob = ((size_t)(b*M_TOT + i*GD + jt*64 + q*4) << 7) + dt*64 + ml;
#pragma unroll
  for (int jf = 0; jf < 4; ++jf)
#pragma unroll
    for (int df = 0; df < 4; ++df)
#pragma unroll
      for (int r = 0; r < 4; ++r)
        outz[ob + ((size_t)(jf*16 + r) << 7) + df*16] = acc[jf][df][r];
}

extern "C" void kernel_launch(void* const* d_in, const int* in_sizes, int n_in,
                              void* d_out, int out_size, void* d_ws, size_t ws_size,
                              hipStream_t stream)
{
  const float* x    = (const float*)d_in[0];
  const float* z    = (const float*)d_in[1];
  const float* grid = (const float*)d_in[2];
  const float* lsp  = (const float*)d_in[3];
  float* out = (float*)d_out;

  char* ws = (char*)d_ws;
  size_t off = 0;
  int*            binStart = (int*)(ws + off);            off += 4*(GD+1)*4;         // 2064
  int*            perm     = (int*)(ws + off);            off += BATCH*NPTS*4;       // 32 KB
  float2*         xs       = (float2*)(ws + off);         off += (size_t)BATCH*ZP*8; // 70 KB
  off = (off + 255) & ~(size_t)255;
  unsigned short* zt       = (unsigned short*)(ws + off); off += (size_t)BATCH*DZDIM*ZP*2; // 2.23MB
  float*          FXf      = (float*)(ws + off);          off += (size_t)BATCH*GD*ZP*4;    // 4.46MB
  float*          FYf      = (float*)(ws + off);          // 4.46MB

  hipLaunchKernelGGL(prep_kernel, dim3(BATCH + 128 + 3), dim3(256), 0, stream,
                     x, grid, out, binStart, xs, zt);
  hipLaunchKernelGGL(scatter_kernel, dim3(GD/4, BATCH), dim3(256), 0, stream,
                     x, binStart, xs, perm);
  hipLaunchKernelGGL(build_kernel, dim3(256 + 1024), dim3(256), 0, stream,
                     z, perm, xs, lsp, zt, FXf, FYf);
  hipLaunchKernelGGL(setconv_mfma_kernel, dim3(GD*BATCH), dim3(256), 0, stream,
                     FXf, FYf, binStart, zt, out + BATCH*GD*GD*2);
}

// Round 9
// 110.663 us; speedup vs baseline: 1.2577x; 1.2080x over previous
//
#include <hip/hip_runtime.h>
#include <hip/hip_bf16.h>

#define BATCH 4
#define NPTS  2048
#define DZDIM 128
#define GD    128
#define M_TOT (GD*GD)
#define ZP    2176      // table row pitch (elements): 2048 data + 128 tail
#define WBIN  15        // +-15 bins: w < 7e-6 outside
#define CHK   64        // K-chunk per barrier (2 MFMA k-tiles)
// LDS chunk buffer layout (bytes): zt 128 rows x 144 | FY 128 rows x 144 | FX 256
#define ZT_OFF 0
#define FY_OFF 18432
#define FX_OFF 36864
#define BUFSZ  37120
#define NSLOT  2320     // 16B slots per buffer: 1152 zt + 1152 fy + 16 fx

typedef __attribute__((ext_vector_type(8))) __bf16 bf16x8;
typedef __attribute__((ext_vector_type(4))) float floatx4;
typedef __attribute__((ext_vector_type(4))) unsigned int uintx4;

__device__ __forceinline__ unsigned int f2bf_bits(float x){
  unsigned int u = __float_as_uint(x);
  u += 0x7FFFu + ((u >> 16) & 1u);
  return u >> 16;
}
__device__ __forceinline__ int point_bin(float px){
  int bin = __float2int_rn((px + 2.0f) * (127.0f / 4.0f));
  return min(GD - 1, max(0, bin));
}
__device__ __forceinline__ unsigned int pk_bf16(float a, float b){
  union { __hip_bfloat162 h2; unsigned int u; } cv;
  cv.h2 = __float22bfloat162_rn(make_float2(a, b));   // v_cvt_pk_bf16_f32 (RNE)
  return cv.u;
}

// ---- prep: hist+scan (0..3) | x_grid bcast (4..131) | xs tail (132) | zt tail (133,134) ----
__global__ __launch_bounds__(256) void prep_kernel(
    const float* __restrict__ x, const float* __restrict__ grid,
    float* __restrict__ out, int* __restrict__ binStart,
    float2* __restrict__ xs, unsigned short* __restrict__ zt)
{
  const int tid = threadIdx.x;
  const int bx  = blockIdx.x;
  if (bx < BATCH){
    __shared__ int h[GD];
    __shared__ int s[GD + 1];
    const int b = bx;
    if (tid < GD) h[tid] = 0;
    __syncthreads();
    for (int n = tid; n < NPTS; n += 256)
      atomicAdd(&h[point_bin(x[(b*NPTS + n)*2])], 1);
    __syncthreads();
    if (tid == 0){
      int acc = 0;
#pragma unroll
      for (int j = 0; j < GD; ++j){ s[j] = acc; acc += h[j]; }
      s[GD] = acc;
    }
    __syncthreads();
    if (tid <= GD) binStart[b*(GD+1) + tid] = s[tid];
  } else if (bx < BATCH + 128){
    int idx = (bx - BATCH) * 256 + tid;       // 0..32767 == GD*GD*2
    float g = grid[idx];
#pragma unroll
    for (int b = 0; b < BATCH; ++b) out[b*(GD*GD*2) + idx] = g;
  } else if (bx == BATCH + 128){
    // xs tail: 4 batches x 128 float2 -> (0,0)
    for (int sIdx = tid; sIdx < BATCH*128; sIdx += 256){
      int b = sIdx >> 7, j = sIdx & 127;
      xs[(size_t)b*ZP + NPTS + j] = make_float2(0.f, 0.f);
    }
  } else {
    // zt tail: 512 rows x 128 elem -> 0 ; 2 blocks x 256 rows
    int row = (bx - (BATCH + 129)) * 256 + tid;   // 0..511 == b*128+dz
    uintx4 zv = {0u, 0u, 0u, 0u};
    uintx4* p = (uintx4*)&zt[(size_t)row*ZP + NPTS];
#pragma unroll
    for (int c = 0; c < 16; ++c) p[c] = zv;
  }
}

// ---- stable scatter into bin-sorted arrays: xs (float2) + perm ----
__global__ __launch_bounds__(256) void scatter_kernel(const float* __restrict__ x,
                                                      const int* __restrict__ binStart,
                                                      float2* __restrict__ xs,
                                                      int* __restrict__ perm){
  const int b = blockIdx.y;
  const int wv = threadIdx.x >> 6, lane = threadIdx.x & 63;
  const int bin = blockIdx.x * 4 + wv;
  int base = binStart[b*(GD+1) + bin];
  const float2* __restrict__ x2 = (const float2*)x;
  for (int n0 = 0; n0 < NPTS; n0 += 64){
    int n = n0 + lane;
    float2 xv = x2[b*NPTS + n];
    bool keep = (point_bin(xv.x) == bin);
    unsigned long long mask = __ballot(keep);
    int pre = __popcll(mask & ((1ull << lane) - 1ull));
    if (keep){
      xs[(size_t)b*ZP + base + pre] = xv;
      perm[b*NPTS + base + pre]   = n;
    }
    base += __popcll(mask);
  }
}

// ---- build: bid<256 -> zt (bf16); bid>=256 -> FX f32 table + FY bf16 table ----
__global__ __launch_bounds__(256) void build_kernel(
    const float* __restrict__ z, const int* __restrict__ perm,
    const float2* __restrict__ xs, const float* __restrict__ lsp,
    unsigned short* __restrict__ zt,
    float* __restrict__ FXf, unsigned short* __restrict__ FYb)
{
  const int tid = threadIdx.x;
  const int bid = blockIdx.x;
  if (bid < 256){
    const int by = bid >> 5;             // b*2 + half
    const int b = by >> 1, half = by & 1;
    const int j0 = (bid & 31) * 64;
    const int jj = tid & 63;
    const int dq = tid >> 6;             // 0..3
    const int j  = j0 + jj;
    const int n  = perm[b*NPTS + j];
    const float4* __restrict__ z4 = (const float4*)z;
    const long rb = (long)(b*NPTS + n) * 32;
#pragma unroll
    for (int r = 0; r < 4; ++r){
      int c = half*16 + dq*4 + r;        // float4 chunk -> dz = 4c..4c+3
      float4 v = z4[rb + c];
      size_t o = ((size_t)(b*DZDIM + 4*c) * ZP) + j;
      zt[o        ] = (unsigned short)f2bf_bits(v.x);
      zt[o +   ZP ] = (unsigned short)f2bf_bits(v.y);
      zt[o + 2*ZP ] = (unsigned short)f2bf_bits(v.z);
      zt[o + 3*ZP ] = (unsigned short)f2bf_bits(v.w);
    }
  } else {
    const int tb   = bid - 256;          // 0..1023
    const int tbl  = tb & 1;             // 0=FX (x, f32), 1=FY (y, bf16)
    const int b    = (tb >> 1) & 3;
    const int row  = tb >> 3;            // 0..127
    const float step = 4.0f / 127.0f;
    const float g = -2.0f + (float)row * step;
    const float l0 = 1e-5f + log1pf(expf(lsp[0]));
    const float l1 = 1e-5f + log1pf(expf(lsp[1]));
    const float LOG2E = 1.4426950408889634f;
    const float c = tbl ? (-0.5f * LOG2E / (l1*l1)) : (-0.5f * LOG2E / (l0*l0));
    const float4* __restrict__ p4 = (const float4*)(xs + (size_t)b*ZP);
    for (int sIdx = tid; sIdx < ZP/8; sIdx += 256){
      int k0 = sIdx * 8;
      float w[8];
#pragma unroll
      for (int j = 0; j < 4; ++j){
        float4 pp = p4[k0/2 + j];        // two points: (x0,y0,x1,y1)
        float p0 = tbl ? pp.y : pp.x;
        float p1 = tbl ? pp.w : pp.z;
        float d0 = g - p0, d1 = g - p1;
        w[2*j]   = __builtin_amdgcn_exp2f((c*d0)*d0);
        w[2*j+1] = __builtin_amdgcn_exp2f((c*d1)*d1);
      }
      if (tbl){
        unsigned short* T = FYb + (size_t)(b*GD + row)*ZP;
        uintx4 u;
#pragma unroll
        for (int j = 0; j < 4; ++j)
          u[j] = f2bf_bits(w[2*j]) | (f2bf_bits(w[2*j+1]) << 16);
        *(uintx4*)&T[k0] = u;
      } else {
        float* T = FXf + (size_t)(b*GD + row)*ZP;
        *(float4*)(T + k0)     = make_float4(w[0], w[1], w[2], w[3]);
        *(float4*)(T + k0 + 4) = make_float4(w[4], w[5], w[6], w[7]);
      }
    }
  }
}

// ---- main: fully-staged chunk pipeline. block = (b,i) = 128j x 128dz, 4 waves 64j x 64dz.
// Per chunk, glds stages zt(bf16) + FY(bf16) + FX(f32); compute phase (~1900 cyc) >>
// glds latency -> barrier drain is free. NO global loads inside compute.
__global__ __launch_bounds__(256, 2) void setconv_mfma_kernel(
    const float* __restrict__ FXf, const unsigned short* __restrict__ FYb,
    const int* __restrict__ binStart, const unsigned short* __restrict__ zt,
    float* __restrict__ outz)
{
  __shared__ __align__(16) unsigned char Zl[2][BUFSZ];   // 2 x 37120 B

  const int tid = threadIdx.x, lane = tid & 63, wv = tid >> 6;
  const int q  = lane >> 4, ml = lane & 15;
  const int jt = wv & 1, dt = wv >> 1;     // wave tile: j-half, d-half
  const int bid = blockIdx.x;              // 512 blocks
  const int g   = bid & 7;                 // XCD band
  const int s   = bid >> 3;
  const int b   = s & 3;
  const int il  = s >> 2;                  // 0..15
  const int i   = g*16 + il;

  const int lo   = binStart[b*(GD+1) + max(0, i - WBIN)];
  const int hi   = binStart[b*(GD+1) + min(GD-1, i + WBIN) + 1];
  const int lo32 = lo & ~31;
  const int C    = (hi - lo32 + CHK - 1) / CHK;

  const unsigned short* __restrict__ ztb = zt  + (size_t)b*DZDIM*ZP;
  const unsigned short* __restrict__ fyb = FYb + (size_t)b*GD*ZP;
  const float*          __restrict__ fxr = FXf + (size_t)(b*GD + i)*ZP;

  floatx4 acc[4][4];
#pragma unroll
  for (int jf = 0; jf < 4; ++jf)
#pragma unroll
    for (int df = 0; df < 4; ++df) acc[jf][df] = (floatx4){0.f,0.f,0.f,0.f};

  auto stage = [&](int buf, int c){
    const int k0 = lo32 + c*CHK;
#pragma unroll
    for (int it = 0; it < 10; ++it){
      int sl = it*256 + tid;               // 16B slot in buffer
      if (sl < NSLOT){
        const void* gp;
        if (sl < 1152){
          int row = sl / 9, cc = sl - row*9; if (cc > 7) cc = 7;
          gp = ztb + (size_t)row*ZP + k0 + cc*8;
        } else if (sl < 2304){
          int t = sl - 1152;
          int row = t / 9, cc = t - row*9; if (cc > 7) cc = 7;
          gp = fyb + (size_t)row*ZP + k0 + cc*8;
        } else {
          gp = fxr + k0 + (sl - 2304)*4;
        }
        __builtin_amdgcn_global_load_lds(
            (const __attribute__((address_space(1))) unsigned int*)gp,
            (__attribute__((address_space(3))) unsigned int*)(&Zl[buf][0] + (size_t)sl*16),
            16, 0, 0);
      }
    }
  };

  auto compute = [&](int buf){
    const unsigned char* zb = &Zl[buf][0];
#pragma unroll
    for (int kt = 0; kt < 2; ++kt){
      // FX: lane's 8 f32 (broadcast across ml -> conflict-free)
      float4 fxa = *(const float4*)(zb + FX_OFF + (kt*32 + q*8)*4);
      float4 fxb = *(const float4*)(zb + FX_OFF + (kt*32 + q*8)*4 + 16);
      float fx[8] = {fxa.x,fxa.y,fxa.z,fxa.w, fxb.x,fxb.y,fxb.z,fxb.w};
      // A-frags: af[jf] = bf16(FX * FY)
      bf16x8 af[4];
#pragma unroll
      for (int jf = 0; jf < 4; ++jf){
        int m = jt*64 + jf*16 + ml;
        uintx4 fy = *(const uintx4*)(zb + FY_OFF + (size_t)m*144 + kt*64 + q*16);
        uintx4 u;
#pragma unroll
        for (int j = 0; j < 4; ++j){
          float flo = __uint_as_float(fy[j] << 16);          // k = 2j
          float fhi = __uint_as_float(fy[j] & 0xffff0000u);  // k = 2j+1
          u[j] = pk_bf16(flo * fx[2*j], fhi * fx[2*j+1]);
        }
        union { uintx4 uu; bf16x8 v; } cv; cv.uu = u;
        af[jf] = cv.v;
      }
      // B-frags from staged zt
      bf16x8 bf[4];
#pragma unroll
      for (int df = 0; df < 4; ++df){
        int d = dt*64 + df*16 + ml;
        bf[df] = *(const bf16x8*)(zb + ZT_OFF + (size_t)d*144 + kt*64 + q*16);
      }
#pragma unroll
      for (int jf = 0; jf < 4; ++jf)
#pragma unroll
        for (int df = 0; df < 4; ++df)
          acc[jf][df] = __builtin_amdgcn_mfma_f32_16x16x32_bf16(af[jf], bf[df], acc[jf][df], 0, 0, 0);
    }
  };

  if (C > 0){
    stage(0, 0);
    __syncthreads();
    for (int c = 0; c < C; ++c){
      if (c + 1 < C) stage((c + 1) & 1, c + 1);   // in flight across whole compute phase
      compute(c & 1);
      __syncthreads();
    }
  }

  // epilogue: C/D col(d)=ml, row(j)=q*4+r
  const size_t ob = ((size_t)(b*M_TOT + i*GD + jt*64 + q*4) << 7) + dt*64 + ml;
#pragma unroll
  for (int jf = 0; jf < 4; ++jf)
#pragma unroll
    for (int df = 0; df < 4; ++df)
#pragma unroll
      for (int r = 0; r < 4; ++r)
        outz[ob + ((size_t)(jf*16 + r) << 7) + df*16] = acc[jf][df][r];
}

extern "C" void kernel_launch(void* const* d_in, const int* in_sizes, int n_in,
                              void* d_out, int out_size, void* d_ws, size_t ws_size,
                              hipStream_t stream)
{
  const float* x    = (const float*)d_in[0];
  const float* z    = (const float*)d_in[1];
  const float* grid = (const float*)d_in[2];
  const float* lsp  = (const float*)d_in[3];
  float* out = (float*)d_out;

  char* ws = (char*)d_ws;
  size_t off = 0;
  int*            binStart = (int*)(ws + off);            off += 4*(GD+1)*4;         // 2064
  int*            perm     = (int*)(ws + off);            off += BATCH*NPTS*4;       // 32 KB
  float2*         xs       = (float2*)(ws + off);         off += (size_t)BATCH*ZP*8; // 70 KB
  off = (off + 255) & ~(size_t)255;
  unsigned short* zt       = (unsigned short*)(ws + off); off += (size_t)BATCH*DZDIM*ZP*2; // 2.23MB
  float*          FXf      = (float*)(ws + off);          off += (size_t)BATCH*GD*ZP*4;    // 4.46MB
  unsigned short* FYb      = (unsigned short*)(ws + off); // 2.23MB

  hipLaunchKernelGGL(prep_kernel, dim3(BATCH + 128 + 3), dim3(256), 0, stream,
                     x, grid, out, binStart, xs, zt);
  hipLaunchKernelGGL(scatter_kernel, dim3(GD/4, BATCH), dim3(256), 0, stream,
                     x, binStart, xs, perm);
  hipLaunchKernelGGL(build_kernel, dim3(256 + 1024), dim3(256), 0, stream,
                     z, perm, xs, lsp, zt, FXf, FYb);
  hipLaunchKernelGGL(setconv_mfma_kernel, dim3(GD*BATCH), dim3(256), 0, stream,
                     FXf, FYb, binStart, zt, out + BATCH*GD*GD*2);
}